// Round 1
// baseline (271.529 us; speedup 1.0000x reference)
//
#include <hip/hip_runtime.h>
#include <math.h>

// Problem constants
#define NVEC   65536      // B*H*W = 64*32*32
#define CDIM   64
#define KBOOK  1024
#define NTOT   4194304    // B*C*H*W
#define KSPLIT 4
#define KCHUNK (KBOOK / KSPLIT)   // 256

// d_out layout (float32): [quantized_z: NTOT][quantized_z_st: NTOT][indices: NVEC][perplexity: 1]
// workspace: u64 keys[NVEC] @0 ; float se[KBOOK] @524288 ; int hist[KBOOK] @528384

#define FOR64(M) \
  M(0) M(1) M(2) M(3) M(4) M(5) M(6) M(7) \
  M(8) M(9) M(10) M(11) M(12) M(13) M(14) M(15) \
  M(16) M(17) M(18) M(19) M(20) M(21) M(22) M(23) \
  M(24) M(25) M(26) M(27) M(28) M(29) M(30) M(31) \
  M(32) M(33) M(34) M(35) M(36) M(37) M(38) M(39) \
  M(40) M(41) M(42) M(43) M(44) M(45) M(46) M(47) \
  M(48) M(49) M(50) M(51) M(52) M(53) M(54) M(55) \
  M(56) M(57) M(58) M(59) M(60) M(61) M(62) M(63)

// init keys, zero hist, and compute se (||e_k||^2, numpy pairwise 8-acc, rn intrinsics)
__global__ void prep_kernel(const float* __restrict__ cb, unsigned long long* __restrict__ keys,
                            float* __restrict__ se, int* __restrict__ hist) {
    int t = blockIdx.x * 256 + threadIdx.x;   // grid 256 -> t in [0, NVEC)
    keys[t] = 0xFFFFFFFFFFFFFFFFull;
    if (t < KBOOK) {
        hist[t] = 0;
        const float* row = cb + t * CDIM;
        float r[8];
#pragma unroll
        for (int j = 0; j < 8; ++j) r[j] = __fmul_rn(row[j], row[j]);
#pragma unroll
        for (int i = 8; i < 64; i += 8)
#pragma unroll
            for (int j = 0; j < 8; ++j) r[j] = __fadd_rn(r[j], __fmul_rn(row[i + j], row[i + j]));
        se[t] = __fadd_rn(__fadd_rn(__fadd_rn(r[0], r[1]), __fadd_rn(r[2], r[3])),
                          __fadd_rn(__fadd_rn(r[4], r[5]), __fadd_rn(r[6], r[7])));
    }
}

// Bit-exact dists = fl(fl(sx+se_k) - a_nk), a = ascending-c fmaf chain on zx=2z.
// z held as 64 NAMED scalars, pinned via opaque asm.
// amdgpu_waves_per_eu(4,4): occupancy MAX = 4 waves/EU -> VGPR budget 128.
// ROUND-6 FIX: rocprof showed VGPR_Count=52 -> the one-time PINZ did NOT keep
// z in arch VGPRs; the scheduler parked them in AGPRs and paid a
// v_accvgpr_read per fmaf (268 vs 140 VALU instr per k-pair -> measured
// 182us vs 60us VALU floor). Re-pin all 64 z_c INSIDE the k-loop: moving to
// AGPR between per-iteration pins would cost read+write each iter, so the
// allocator must keep them in arch VGPRs (~85 of the 128 budget).
__launch_bounds__(128)
__attribute__((amdgpu_waves_per_eu(4, 4)))
__global__ void argmin_kernel(const float* __restrict__ z, const float* __restrict__ cb,
                              const float* __restrict__ se,
                              unsigned long long* __restrict__ keys) {
    const int t = threadIdx.x;
    const int n = blockIdx.x * 128 + t;
    const int k0 = blockIdx.y * KCHUNK;
    const int b = n >> 10, hw = n & 1023;
    const float* zb = z + (size_t)b * (CDIM * 1024) + hw;

    float r0_, r1_, r2_, r3_, r4_, r5_, r6_, r7_;
    // zx = 2*z (exact); sx = numpy pairwise 8-acc sum of fl(z^2)
#define LOADZ(c)                                                        \
    float z_##c; {                                                      \
        float zc = zb[(c) * 1024];                                      \
        z_##c = zc + zc;                                                \
        float q = __fmul_rn(zc, zc);                                    \
        if ((c) < 8) { if ((c)==0) r0_=q; else if ((c)==1) r1_=q; else if ((c)==2) r2_=q; \
                       else if ((c)==3) r3_=q; else if ((c)==4) r4_=q; else if ((c)==5) r5_=q; \
                       else if ((c)==6) r6_=q; else r7_=q; }            \
        else { switch ((c) & 7) {                                       \
            case 0: r0_ = __fadd_rn(r0_, q); break;                     \
            case 1: r1_ = __fadd_rn(r1_, q); break;                     \
            case 2: r2_ = __fadd_rn(r2_, q); break;                     \
            case 3: r3_ = __fadd_rn(r3_, q); break;                     \
            case 4: r4_ = __fadd_rn(r4_, q); break;                     \
            case 5: r5_ = __fadd_rn(r5_, q); break;                     \
            case 6: r6_ = __fadd_rn(r6_, q); break;                     \
            default: r7_ = __fadd_rn(r7_, q); break; } }                \
    }
    FOR64(LOADZ)
#undef LOADZ
    const float sx = __fadd_rn(__fadd_rn(__fadd_rn(r0_, r1_), __fadd_rn(r2_, r3_)),
                               __fadd_rn(__fadd_rn(r4_, r5_), __fadd_rn(r6_, r7_)));

    // Opaque SSA def: blocks remat of the z loads inside the k-loop.
#define PINZ(c) asm volatile("" : "+v"(z_##c));
    FOR64(PINZ)
#undef PINZ

    float best = 3.4e38f;
    int bi = k0;

    for (int k = k0; k < k0 + KCHUNK; k += 2) {
        // Re-pin every iteration: forces z_c to live in arch VGPRs across the
        // whole loop (defeats the AGPR-parking that showed as VGPR_Count=52).
        // Empty asm, no memory clobber: s_loads of cb/se still hoist freely.
#define PINZL(c) asm volatile("" : "+v"(z_##c));
        FOR64(PINZL)
#undef PINZL
        const float* __restrict__ row = cb + (size_t)k * CDIM;  // wave-uniform -> s_load
        float a0 = 0.f, a1 = 0.f;                               // 2 indep fmaf chains
#define FMASTEP(c)                              \
        a0 = fmaf(z_##c, row[(c)], a0);         \
        a1 = fmaf(z_##c, row[(c) + 64], a1);
        FOR64(FMASTEP)
#undef FMASTEP
        const float d0 = __fsub_rn(__fadd_rn(sx, se[k]), a0);
        const float d1 = __fsub_rn(__fadd_rn(sx, se[k + 1]), a1);
        if (d0 < best) { best = d0; bi = k; }        // strict <, ascending k: first-min
        if (d1 < best) { best = d1; bi = k + 1; }
    }

    // ordered-float key: monotonic uint32 over all floats; idx in low bits
    unsigned int ob = __float_as_uint(best);
    ob = (ob & 0x80000000u) ? ~ob : (ob | 0x80000000u);
    atomicMin(&keys[n], ((unsigned long long)ob << 32) | (unsigned int)bi);
}

// quantized_z = cb[idx]; quantized_z_st = fl(z + fl(q - z)); float4-vectorized
__global__ void scatter_kernel(const float* __restrict__ z, const float* __restrict__ cb,
                               const unsigned long long* __restrict__ keys,
                               float* __restrict__ out) {
    const int o = (blockIdx.x * 256 + threadIdx.x) * 4;    // [0, NTOT), step 4
    const int b = o >> 16, c = (o >> 10) & 63, hw = o & 1023;
    const int n = (b << 10) | hw;
    float q[4];
#pragma unroll
    for (int j = 0; j < 4; ++j) {
        const int k = (int)(keys[n + j] & 0xFFFFFFFFu);
        q[j] = cb[k * CDIM + c];
    }
    const float4 zv = *(const float4*)(z + o);
    *(float4*)(out + o) = make_float4(q[0], q[1], q[2], q[3]);
    float4 st;
    st.x = __fadd_rn(zv.x, __fsub_rn(q[0], zv.x));
    st.y = __fadd_rn(zv.y, __fsub_rn(q[1], zv.y));
    st.z = __fadd_rn(zv.z, __fsub_rn(q[2], zv.z));
    st.w = __fadd_rn(zv.w, __fsub_rn(q[3], zv.w));
    *(float4*)(out + NTOT + o) = st;
}

// histogram + indices-as-float
__global__ void hist_kernel(const unsigned long long* __restrict__ keys, int* __restrict__ hist,
                            float* __restrict__ outIdxF) {
    __shared__ int lh[KBOOK];
    for (int i = threadIdx.x; i < KBOOK; i += 256) lh[i] = 0;
    __syncthreads();
    const int n = blockIdx.x * 256 + threadIdx.x;          // grid = 256 blocks
    const int k = (int)(keys[n] & 0xFFFFFFFFu);
    outIdxF[n] = (float)k;
    atomicAdd(&lh[k], 1);
    __syncthreads();
    for (int i = threadIdx.x; i < KBOOK; i += 256)
        if (lh[i]) atomicAdd(&hist[i], lh[i]);
}

__global__ void perp_kernel(const int* __restrict__ hist, float* __restrict__ out) {
    __shared__ double partial[16];
    const int t = threadIdx.x;  // 1024 threads
    const int c = hist[t];
    double term = 0.0;
    if (c > 0) { double p = (double)c / (double)NVEC; term = p * log(p); }
    for (int off = 32; off > 0; off >>= 1) term += __shfl_down(term, off);
    if ((t & 63) == 0) partial[t >> 6] = term;
    __syncthreads();
    if (t == 0) {
        double s = 0.0;
        for (int i = 0; i < 16; ++i) s += partial[i];
        out[2 * NTOT + NVEC] = (float)exp(-s);
    }
}

extern "C" void kernel_launch(void* const* d_in, const int* in_sizes, int n_in,
                              void* d_out, int out_size, void* d_ws, size_t ws_size,
                              hipStream_t stream) {
    const float* z  = (const float*)d_in[0];   // [64,64,32,32]
    const float* cb = (const float*)d_in[1];   // [1024,64]
    float* out = (float*)d_out;

    char* ws = (char*)d_ws;
    unsigned long long* keys = (unsigned long long*)(ws + 0);
    float* se   = (float*)(ws + 524288);
    int*   hist = (int*)(ws + 528384);

    prep_kernel<<<256, 256, 0, stream>>>(cb, keys, se, hist);
    dim3 ag(NVEC / 128, KSPLIT);
    argmin_kernel<<<ag, 128, 0, stream>>>(z, cb, se, keys);
    scatter_kernel<<<NTOT / 1024, 256, 0, stream>>>(z, cb, keys, out);
    hist_kernel<<<NVEC / 256, 256, 0, stream>>>(keys, hist, out + 2 * NTOT);
    perp_kernel<<<1, 1024, 0, stream>>>(hist, out);
}

// Round 2
// 263.437 us; speedup vs baseline: 1.0307x; 1.0307x over previous
//
#include <hip/hip_runtime.h>
#include <math.h>

// Problem constants
#define NVEC   65536      // B*H*W
#define CDIM   64
#define KBOOK  1024
#define NTOT   4194304    // B*C*H*W

// d_out layout (float32): [quantized_z: NTOT][quantized_z_st: NTOT][indices: NVEC][perplexity: 1]
// workspace (unchanged footprint): u64 keys[NVEC] @0 ; float se[KBOOK] @524288 ; int hist[KBOOK] @528384
// TRANSIENT scratch lives in d_out's quantized_z region (overwritten by scatter AFTER last read):
//   cand u32[NVEC][4] @out+0 (1MB) ; cbh bf16[1024][64] @out+1MB (128KB) ; cbl @out+1.125MB (128KB)
// Ordering: prep(writes cbh/cbl) -> approx(reads cbh/cbl, writes cand) -> rescore(reads cand,
// writes keys) -> scatter(overwrites out) -> hist -> perp.  All same-stream: safe.

typedef __bf16 bf16x8 __attribute__((ext_vector_type(8)));
typedef float  f32x4  __attribute__((ext_vector_type(4)));

// prep: zero hist; exact se (pairwise 8-acc, rn intrinsics); pack codebook hi/lo bf16.
__global__ void prep_kernel(const float* __restrict__ cb, float* __restrict__ se,
                            int* __restrict__ hist, __bf16* __restrict__ cbh,
                            __bf16* __restrict__ cbl) {
    const int t = blockIdx.x * 256 + threadIdx.x;   // grid 4x256 -> t in [0,1024)
    hist[t] = 0;
    const float* row = cb + t * CDIM;
    float r[8];
#pragma unroll
    for (int j = 0; j < 8; ++j) r[j] = __fmul_rn(row[j], row[j]);
#pragma unroll
    for (int i = 8; i < 64; i += 8)
#pragma unroll
        for (int j = 0; j < 8; ++j) r[j] = __fadd_rn(r[j], __fmul_rn(row[i + j], row[i + j]));
    se[t] = __fadd_rn(__fadd_rn(__fadd_rn(r[0], r[1]), __fadd_rn(r[2], r[3])),
                      __fadd_rn(__fadd_rn(r[4], r[5]), __fadd_rn(r[6], r[7])));
    // hi/lo split: e = eh + el + O(2^-18 |e|); e - (float)eh is exact in fp32.
#pragma unroll
    for (int c = 0; c < 64; ++c) {
        float e = row[c];
        __bf16 h = (__bf16)e;
        cbh[t * 64 + c] = h;
        cbl[t * 64 + c] = (__bf16)(e - (float)h);
    }
}

// MFMA approx pass.  d'(n,k) = se_k + m.e_k, m = -2z, via 3-term bf16 hi/lo
// (mh*eh + mh*el + ml*eh; dropped terms ~1e-6 abs vs distance spacing ~4e-3).
// Mapping (gfx950 16x16x32 bf16, C/D verified m89): A = codebook tile (M-dim = k),
// B = z fragments (N-dim = n).  A-frag: lane holds A[l&15][8*(l>>4)+j];
// B-frag: lane holds B[8*(l>>4)+j][l&15]; D: col = l&15 (n), row = 4*(l>>4)+reg (k).
// se folded into acc init (D = se + A.B).  Per-lane: 4 k-rows x 1 n over 64 tiles
// => top-2 over a disjoint 256-k subset; union over 4 lane-groups = 8 cand/n.
// Exact-argmin-in-set fails only if >=2 same-subset competitors within ~2e-6: P ~ 5e-3 total.
__launch_bounds__(256)
__global__ void approx_kernel(const float* __restrict__ z, const __bf16* __restrict__ cbh,
                              const __bf16* __restrict__ cbl, const float* __restrict__ se,
                              unsigned int* __restrict__ cand) {
    const int tid = threadIdx.x;
    const int w = tid >> 6;           // wave in block
    const int l = tid & 63;           // lane
    const int la = l & 15;            // A-row offset / D-col (n) offset
    const int g  = l >> 4;            // lane group
    const int n = blockIdx.x * 64 + w * 16 + la;
    const int b = n >> 10, hw = n & 1023;
    const float* zb = z + (size_t)b * (CDIM * 1024) + hw;   // + c*1024

    // B-fragments (constant over the whole k-loop): z cols for this lane's n.
    bf16x8 mh0, ml0, mh1, ml1;
#pragma unroll
    for (int j = 0; j < 8; ++j) {
        {   // K-step 0: c in [0,32)
            float zc = zb[(g * 8 + j) * 1024];
            float m  = -2.0f * zc;
            __bf16 h = (__bf16)m;
            mh0[j] = h; ml0[j] = (__bf16)(m - (float)h);
        }
        {   // K-step 1: c in [32,64)
            float zc = zb[(32 + g * 8 + j) * 1024];
            float m  = -2.0f * zc;
            __bf16 h = (__bf16)m;
            mh1[j] = h; ml1[j] = (__bf16)(m - (float)h);
        }
    }

    float b1 = 3.4e38f, b2 = 3.4e38f;
    int   k1 = 0,       k2 = 0;
    const int kv = g * 4;             // D-row base for this lane

    for (int tt = 0; tt < 64; ++tt) {
        const int k0 = tt * 16;
        f32x4 acc = *(const f32x4*)(se + k0 + kv);     // acc init = se rows (L1-hot)
        const size_t abase = (size_t)((k0 + la) << 6) + 8 * g;
        bf16x8 ah0 = *(const bf16x8*)(cbh + abase);
        bf16x8 ah1 = *(const bf16x8*)(cbh + abase + 32);
        bf16x8 al0 = *(const bf16x8*)(cbl + abase);
        bf16x8 al1 = *(const bf16x8*)(cbl + abase + 32);
        acc = __builtin_amdgcn_mfma_f32_16x16x32_bf16(ah0, mh0, acc, 0, 0, 0);
        acc = __builtin_amdgcn_mfma_f32_16x16x32_bf16(ah1, mh1, acc, 0, 0, 0);
        acc = __builtin_amdgcn_mfma_f32_16x16x32_bf16(al0, mh0, acc, 0, 0, 0);
        acc = __builtin_amdgcn_mfma_f32_16x16x32_bf16(al1, mh1, acc, 0, 0, 0);
        acc = __builtin_amdgcn_mfma_f32_16x16x32_bf16(ah0, ml0, acc, 0, 0, 0);
        acc = __builtin_amdgcn_mfma_f32_16x16x32_bf16(ah1, ml1, acc, 0, 0, 0);
        // top-2 insert of the 4 row-scores (strict <: earlier k kept on approx ties)
#pragma unroll
        for (int r = 0; r < 4; ++r) {
            const float d = acc[r];
            const int  kt = k0 + kv + r;
            const bool c1 = d < b1, c2 = d < b2;
            b2 = c1 ? b1 : (c2 ? d : b2);  k2 = c1 ? k1 : (c2 ? kt : k2);
            b1 = c1 ? d  : b1;             k1 = c1 ? kt : k1;
        }
    }
    cand[n * 4 + g] = (unsigned int)k1 | ((unsigned int)k2 << 16);
}

// Exact rescore of the 8 candidates per n.  Bit-identical chain to the reference:
// zx = 2z; a_k = ascending-c fmaf chain; sx = pairwise 8-acc of fl(z^2);
// d = fl(fl(sx + se_k) - a_k).  Min via ordered-u64 key (d bits || k): first-min semantics.
__global__ void rescore_kernel(const float* __restrict__ z, const float* __restrict__ cb,
                               const float* __restrict__ se,
                               const unsigned int* __restrict__ cand,
                               unsigned long long* __restrict__ keys) {
    const int n = blockIdx.x * 256 + threadIdx.x;   // grid 256x256
    int ks[8];
#pragma unroll
    for (int g = 0; g < 4; ++g) {
        const unsigned int p = cand[n * 4 + g];
        ks[2 * g]     = (int)(p & 0xFFFFu);
        ks[2 * g + 1] = (int)(p >> 16);
    }
    const int b = n >> 10, hw = n & 1023;
    const float* zb = z + (size_t)b * (CDIM * 1024) + hw;

    float zx[64], r[8];
#pragma unroll
    for (int j = 0; j < 8; ++j) {
        const float zc = zb[j * 1024];
        zx[j] = zc + zc;
        r[j] = __fmul_rn(zc, zc);
    }
#pragma unroll
    for (int c = 8; c < 64; ++c) {
        const float zc = zb[c * 1024];
        zx[c] = zc + zc;
        r[c & 7] = __fadd_rn(r[c & 7], __fmul_rn(zc, zc));
    }
    const float sx = __fadd_rn(__fadd_rn(__fadd_rn(r[0], r[1]), __fadd_rn(r[2], r[3])),
                               __fadd_rn(__fadd_rn(r[4], r[5]), __fadd_rn(r[6], r[7])));

    float a[8];
#pragma unroll
    for (int i = 0; i < 8; ++i) a[i] = 0.0f;
    const float4* cb4 = (const float4*)cb;
#pragma unroll
    for (int q = 0; q < 16; ++q) {               // c = 4q .. 4q+3, ascending per chain
#pragma unroll
        for (int i = 0; i < 8; ++i) {
            const float4 ev = cb4[ks[i] * 16 + q];
            a[i] = fmaf(zx[4 * q],     ev.x, a[i]);
            a[i] = fmaf(zx[4 * q + 1], ev.y, a[i]);
            a[i] = fmaf(zx[4 * q + 2], ev.z, a[i]);
            a[i] = fmaf(zx[4 * q + 3], ev.w, a[i]);
        }
    }
    unsigned long long best = ~0ull;
#pragma unroll
    for (int i = 0; i < 8; ++i) {
        const float d = __fsub_rn(__fadd_rn(sx, se[ks[i]]), a[i]);
        unsigned int ob = __float_as_uint(d);
        ob = (ob & 0x80000000u) ? ~ob : (ob | 0x80000000u);
        const unsigned long long key = ((unsigned long long)ob << 32) | (unsigned int)ks[i];
        if (key < best) best = key;
    }
    keys[n] = best;    // single writer: plain store
}

// quantized_z = cb[idx]; quantized_z_st = fl(z + fl(q - z)); float4-vectorized
__global__ void scatter_kernel(const float* __restrict__ z, const float* __restrict__ cb,
                               const unsigned long long* __restrict__ keys,
                               float* __restrict__ out) {
    const int o = (blockIdx.x * 256 + threadIdx.x) * 4;    // [0, NTOT), step 4
    const int b = o >> 16, c = (o >> 10) & 63, hw = o & 1023;
    const int n = (b << 10) | hw;
    float q[4];
#pragma unroll
    for (int j = 0; j < 4; ++j) {
        const int k = (int)(keys[n + j] & 0xFFFFFFFFu);
        q[j] = cb[k * CDIM + c];
    }
    const float4 zv = *(const float4*)(z + o);
    *(float4*)(out + o) = make_float4(q[0], q[1], q[2], q[3]);
    float4 st;
    st.x = __fadd_rn(zv.x, __fsub_rn(q[0], zv.x));
    st.y = __fadd_rn(zv.y, __fsub_rn(q[1], zv.y));
    st.z = __fadd_rn(zv.z, __fsub_rn(q[2], zv.z));
    st.w = __fadd_rn(zv.w, __fsub_rn(q[3], zv.w));
    *(float4*)(out + NTOT + o) = st;
}

// histogram + indices-as-float
__global__ void hist_kernel(const unsigned long long* __restrict__ keys, int* __restrict__ hist,
                            float* __restrict__ outIdxF) {
    __shared__ int lh[KBOOK];
    for (int i = threadIdx.x; i < KBOOK; i += 256) lh[i] = 0;
    __syncthreads();
    const int n = blockIdx.x * 256 + threadIdx.x;          // grid = 256 blocks
    const int k = (int)(keys[n] & 0xFFFFFFFFu);
    outIdxF[n] = (float)k;
    atomicAdd(&lh[k], 1);
    __syncthreads();
    for (int i = threadIdx.x; i < KBOOK; i += 256)
        if (lh[i]) atomicAdd(&hist[i], lh[i]);
}

__global__ void perp_kernel(const int* __restrict__ hist, float* __restrict__ out) {
    __shared__ double partial[16];
    const int t = threadIdx.x;  // 1024 threads
    const int c = hist[t];
    double term = 0.0;
    if (c > 0) { double p = (double)c / (double)NVEC; term = p * log(p); }
    for (int off = 32; off > 0; off >>= 1) term += __shfl_down(term, off);
    if ((t & 63) == 0) partial[t >> 6] = term;
    __syncthreads();
    if (t == 0) {
        double s = 0.0;
        for (int i = 0; i < 16; ++i) s += partial[i];
        out[2 * NTOT + NVEC] = (float)exp(-s);
    }
}

extern "C" void kernel_launch(void* const* d_in, const int* in_sizes, int n_in,
                              void* d_out, int out_size, void* d_ws, size_t ws_size,
                              hipStream_t stream) {
    const float* z  = (const float*)d_in[0];   // [64,64,32,32]
    const float* cb = (const float*)d_in[1];   // [1024,64]
    float* out = (float*)d_out;

    char* ws = (char*)d_ws;
    unsigned long long* keys = (unsigned long long*)(ws + 0);
    float* se   = (float*)(ws + 524288);
    int*   hist = (int*)(ws + 528384);

    // Transient scratch inside d_out's quantized_z region (overwritten by scatter later).
    char* outB = (char*)d_out;
    unsigned int* cand = (unsigned int*)(outB);                         // 1 MB
    __bf16* cbh = (__bf16*)(outB + (1 << 20));                          // 128 KB
    __bf16* cbl = (__bf16*)(outB + (1 << 20) + (128 << 10));            // 128 KB

    prep_kernel<<<4, 256, 0, stream>>>(cb, se, hist, cbh, cbl);
    approx_kernel<<<NVEC / 64, 256, 0, stream>>>(z, cbh, cbl, se, cand);
    rescore_kernel<<<NVEC / 256, 256, 0, stream>>>(z, cb, se, cand, keys);
    scatter_kernel<<<NTOT / 1024, 256, 0, stream>>>(z, cb, keys, out);
    hist_kernel<<<NVEC / 256, 256, 0, stream>>>(keys, hist, out + 2 * NTOT);
    perp_kernel<<<1, 1024, 0, stream>>>(hist, out);
}